// Round 1
// baseline (370.258 us; speedup 1.0000x reference)
//
#include <hip/hip_runtime.h>

#define G_ 19
#define A_ 5
#define C_ 20
#define BS_ 16
#define N_ (G_*G_*A_)        // 1805
#define NE_ (BS_*N_)         // 28880
#define JCHUNKS 4
#define JCAP ((N_ + JCHUNKS - 1)/JCHUNKS)   // 452
#define ICHUNK 256
#define ICHUNKS ((N_ + ICHUNK - 1)/ICHUNK)  // 8
#define EPSF 1e-8f

__device__ __forceinline__ float sigmoidf_(float x) {
    return 1.0f / (1.0f + __expf(-x));
}

__device__ __forceinline__ void block_reduce_add(float local, float* out) {
    // 256 threads = 4 waves of 64
    for (int off = 32; off; off >>= 1) local += __shfl_down(local, off);
    __shared__ float red[4];
    int wid = threadIdx.x >> 6, lane = threadIdx.x & 63;
    if (lane == 0) red[wid] = local;
    __syncthreads();
    if (threadIdx.x == 0) atomicAdd(out, red[0] + red[1] + red[2] + red[3]);
}

__global__ __launch_bounds__(256) void k1_elemwise(
    const float* __restrict__ pred, const float* __restrict__ gt,
    const float* __restrict__ anch, const int* __restrict__ epoch_p,
    float* __restrict__ out,
    unsigned* __restrict__ cntp, unsigned* __restrict__ cntn,
    float4* __restrict__ gtc_box, float* __restrict__ gtc_ab,
    float4* __restrict__ pnc_box, float* __restrict__ pnc_val,
    unsigned* __restrict__ flags)
{
    int e = blockIdx.x * 256 + threadIdx.x;
    float local = 0.f;
    if (e < NE_) {
        flags[e] = 0u;
        int b  = e / N_;
        int n  = e - b * N_;
        int a  = n % A_;
        int g2 = (n / A_) % G_;
        int g1 = n / (A_ * G_);
        const float* P = pred + (size_t)e * 25;
        const float* T = gt   + (size_t)e * 25;
        float px = P[0], py = P[1], pw = P[2], ph = P[3], po = P[4];
        float gx = T[0], gy = T[1], gw = T[2], gh = T[3], go = T[4];
        float aw = anch[a*2+0], ah = anch[a*2+1];

        float sx  = sigmoidf_(px), sy = sigmoidf_(py);
        float pbw = __expf(pw) * aw, pbh = __expf(ph) * ah;
        float gbw = __expf(gw) * aw, gbh = __expf(gh) * ah;

        float cxp = sx + (float)g2, cyp = sy + (float)g1;
        float hwp = pbw * (0.5f * G_), hhp = pbh * (0.5f * G_);
        float px1 = cxp - hwp, py1 = cyp - hhp, px2 = cxp + hwp, py2 = cyp + hhp;

        float cxg = gx + (float)g2, cyg = gy + (float)g1;
        float hwg = gbw * (0.5f * G_), hhg = gbh * (0.5f * G_);
        float gx1 = cxg - hwg, gy1 = cyg - hhg, gx2 = cxg + hwg, gy2 = cyg + hhg;

        float pconf = sigmoidf_(po);
        float area_p = fmaxf(px2 - px1, 0.f) * fmaxf(py2 - py1, 0.f);
        float area_g = fmaxf(gx2 - gx1, 0.f) * fmaxf(gy2 - gy1, 0.f);

        if (*epoch_p < 12) {
            local += 0.01f * (px*px + py*py + pw*pw + ph*ph);
        }
        bool pos = go > 0.5f;
        if (pos) {
            // xywh
            float d0 = gx - sx, d1 = gy - sy, d2 = gw - pw, d3 = gh - ph;
            local += 5.0f * (d0*d0 + d1*d1 + d2*d2 + d3*d3);
            // conf (elementwise IoU)
            float ix1 = fmaxf(px1, gx1), iy1 = fmaxf(py1, gy1);
            float ix2 = fminf(px2, gx2), iy2 = fminf(py2, gy2);
            float iw = fmaxf(ix2 - ix1, 0.f), ih = fmaxf(iy2 - iy1, 0.f);
            float inter = iw * ih;
            float iou = inter / (area_p + area_g - inter + EPSF);
            float dc = iou - pconf;
            local += dc * dc;
            // cls: softmax over 20
            float cl[C_];
            float m = -1e30f;
            #pragma unroll
            for (int c = 0; c < C_; c++) { cl[c] = P[5+c]; m = fmaxf(m, cl[c]); }
            float s = 0.f;
            #pragma unroll
            for (int c = 0; c < C_; c++) { cl[c] = __expf(cl[c] - m); s += cl[c]; }
            float inv = 1.0f / s;
            float acc = 0.f;
            #pragma unroll
            for (int c = 0; c < C_; c++) { float d = T[5+c] - cl[c]*inv; acc += d*d; }
            local += acc;
        }
        local *= (1.0f / BS_);

        // compaction for pairwise pass
        if (pos) {
            unsigned k = atomicAdd(&cntp[b], 1u);
            gtc_box[b*N_ + k] = make_float4(gx1, gy1, gx2, gy2);
            gtc_ab[b*N_ + k]  = area_g;
        } else {
            unsigned k = atomicAdd(&cntn[b], 1u);
            pnc_box[b*N_ + k] = make_float4(px1, py1, px2, py2);
            pnc_val[b*N_ + k] = (0.5f / BS_) * pconf * pconf;  // L_NOOBJ/bs * pconf^2
        }
    }
    block_reduce_add(local, out);
}

__global__ __launch_bounds__(256) void k2_pairmax(
    const unsigned* __restrict__ cntp, const unsigned* __restrict__ cntn,
    const float4* __restrict__ gtc_box, const float* __restrict__ gtc_ab,
    const float4* __restrict__ pnc_box, unsigned* __restrict__ flags)
{
    int b = blockIdx.z, ic = blockIdx.y, jc = blockIdx.x;
    int npos = (int)cntp[b];
    int jstart = jc * JCAP;
    int jlen = min(npos - jstart, JCAP);
    if (jlen <= 0) return;   // uniform exit

    __shared__ float sx1[JCAP], sy1[JCAP], sx2[JCAP], sy2[JCAP], sab[JCAP];
    for (int j = threadIdx.x; j < jlen; j += 256) {
        float4 g = gtc_box[b*N_ + jstart + j];
        sx1[j] = g.x; sy1[j] = g.y; sx2[j] = g.z; sy2[j] = g.w;
        sab[j] = gtc_ab[b*N_ + jstart + j];
    }
    __syncthreads();

    int nn = (int)cntn[b];
    int i = ic * ICHUNK + threadIdx.x;
    if (i >= nn) return;

    float4 p = pnc_box[b*N_ + i];
    float area_a = (p.z - p.x) * (p.w - p.y);
    float c0 = area_a + EPSF;
    float md = -1.0f;
    for (int j = 0; j < jlen; j++) {
        float ix1 = fmaxf(p.x, sx1[j]);
        float iy1 = fmaxf(p.y, sy1[j]);
        float ix2 = fminf(p.z, sx2[j]);
        float iy2 = fminf(p.w, sy2[j]);
        float dx = fmaxf(ix2 - ix1, 0.f);
        float dy = fmaxf(iy2 - iy1, 0.f);
        float inter = dx * dy;
        float u = (c0 + sab[j]) - inter;           // area_a + area_b - inter + eps
        md = fmaxf(md, fmaf(-0.6f, u, inter));     // inter - 0.6*union >= 0  <=>  iou >= 0.6
    }
    if (md >= 0.f) flags[b*N_ + i] = 1u;           // benign same-value race across j-chunks
}

__global__ __launch_bounds__(256) void k3_noobj(
    const unsigned* __restrict__ cntn, const float* __restrict__ pnc_val,
    const unsigned* __restrict__ flags, float* __restrict__ out)
{
    int e = blockIdx.x * 256 + threadIdx.x;
    float local = 0.f;
    if (e < NE_) {
        int b = e / N_;
        int i = e - b * N_;
        if (i < (int)cntn[b] && flags[e] == 0u) local = pnc_val[e];
    }
    block_reduce_add(local, out);
}

extern "C" void kernel_launch(void* const* d_in, const int* in_sizes, int n_in,
                              void* d_out, int out_size, void* d_ws, size_t ws_size,
                              hipStream_t stream) {
    const float* pred  = (const float*)d_in[0];
    const float* gt    = (const float*)d_in[1];
    const float* anch  = (const float*)d_in[2];
    const int*   epoch = (const int*)d_in[3];
    float* out = (float*)d_out;

    char* ws = (char*)d_ws;
    // layout (bytes):
    // [0,64)        cntp[16]
    // [64,128)      cntn[16]
    // [128, +NE*16) gtc_box (float4)
    // ...           gtc_ab  (float)
    // ...           pnc_box (float4)  -- offset 577728, 16B-aligned
    // ...           pnc_val (float)
    // ...           flags   (unsigned)
    unsigned* cntp   = (unsigned*)(ws + 0);
    unsigned* cntn   = (unsigned*)(ws + 64);
    float4*   gtcb   = (float4*)(ws + 128);
    float*    gtcab  = (float*)(ws + 128 + (size_t)NE_*16);
    float4*   pncb   = (float4*)(ws + 128 + (size_t)NE_*16 + (size_t)NE_*4);
    float*    pncv   = (float*)(ws + 128 + (size_t)NE_*16*2 + (size_t)NE_*4);
    unsigned* flags  = (unsigned*)(ws + 128 + (size_t)NE_*16*2 + (size_t)NE_*4*2);

    hipMemsetAsync(d_out, 0, sizeof(float), stream);
    hipMemsetAsync(ws, 0, 128, stream);

    int nblk = (NE_ + 255) / 256;
    k1_elemwise<<<nblk, 256, 0, stream>>>(pred, gt, anch, epoch, out,
                                          cntp, cntn, gtcb, gtcab, pncb, pncv, flags);
    dim3 g2(JCHUNKS, ICHUNKS, BS_);
    k2_pairmax<<<g2, 256, 0, stream>>>(cntp, cntn, gtcb, gtcab, pncb, flags);
    k3_noobj<<<nblk, 256, 0, stream>>>(cntn, pncv, flags, out);
}

// Round 2
// 67.516 us; speedup vs baseline: 5.4840x; 5.4840x over previous
//
#include <hip/hip_runtime.h>

#define G_ 19
#define A_ 5
#define C_ 20
#define BS_ 16
#define N_ (G_*G_*A_)        // 1805
#define NE_ (BS_*N_)         // 28880
#define NBLK1 ((N_ + 255) / 256)            // 8 blocks per batch
#define JCHUNKS 4
#define JCAP ((N_ + JCHUNKS - 1)/JCHUNKS)   // 452
#define ICHUNK 256
#define ICHUNKS ((N_ + ICHUNK - 1)/ICHUNK)  // 8
#define EPSF 1e-8f

__device__ __forceinline__ float sigmoidf_(float x) {
    return 1.0f / (1.0f + __expf(-x));
}

__device__ __forceinline__ void block_reduce_add(float local, float* out) {
    // 256 threads = 4 waves of 64
    for (int off = 32; off; off >>= 1) local += __shfl_down(local, off);
    __shared__ float red[4];
    int wid = threadIdx.x >> 6, lane = threadIdx.x & 63;
    if (lane == 0) red[wid] = local;
    __syncthreads();
    if (threadIdx.x == 0) atomicAdd(out, red[0] + red[1] + red[2] + red[3]);
}

__global__ __launch_bounds__(256) void k1_elemwise(
    const float* __restrict__ pred, const float* __restrict__ gt,
    const float* __restrict__ anch, const int* __restrict__ epoch_p,
    float* __restrict__ out,
    unsigned* __restrict__ cntp, unsigned* __restrict__ cntn,
    float4* __restrict__ gtc_box, float* __restrict__ gtc_ab,
    float4* __restrict__ pnc_box, float* __restrict__ pnc_val,
    unsigned* __restrict__ flags)
{
    int b = blockIdx.y;
    int n = blockIdx.x * 256 + threadIdx.x;
    bool valid = n < N_;
    int e = b * N_ + n;
    float local = 0.f;

    bool pos = false;
    float gx1=0, gy1=0, gx2=0, gy2=0, area_g=0;
    float px1=0, py1=0, px2=0, py2=0, pconf=0;

    if (valid) {
        flags[e] = 0u;
        int a  = n % A_;
        int g2 = (n / A_) % G_;
        int g1 = n / (A_ * G_);
        const float* P = pred + (size_t)e * 25;
        const float* T = gt   + (size_t)e * 25;
        float px = P[0], py = P[1], pw = P[2], ph = P[3], po = P[4];
        float gx = T[0], gy = T[1], gw = T[2], gh = T[3], go = T[4];
        float aw = anch[a*2+0], ah = anch[a*2+1];

        float sx  = sigmoidf_(px), sy = sigmoidf_(py);
        float pbw = __expf(pw) * aw, pbh = __expf(ph) * ah;
        float gbw = __expf(gw) * aw, gbh = __expf(gh) * ah;

        float cxp = sx + (float)g2, cyp = sy + (float)g1;
        float hwp = pbw * (0.5f * G_), hhp = pbh * (0.5f * G_);
        px1 = cxp - hwp; py1 = cyp - hhp; px2 = cxp + hwp; py2 = cyp + hhp;

        float cxg = gx + (float)g2, cyg = gy + (float)g1;
        float hwg = gbw * (0.5f * G_), hhg = gbh * (0.5f * G_);
        gx1 = cxg - hwg; gy1 = cyg - hhg; gx2 = cxg + hwg; gy2 = cyg + hhg;

        pconf = sigmoidf_(po);
        float area_p = fmaxf(px2 - px1, 0.f) * fmaxf(py2 - py1, 0.f);
        area_g = fmaxf(gx2 - gx1, 0.f) * fmaxf(gy2 - gy1, 0.f);

        if (*epoch_p < 12) {
            local += 0.01f * (px*px + py*py + pw*pw + ph*ph);
        }
        pos = go > 0.5f;
        if (pos) {
            // xywh
            float d0 = gx - sx, d1 = gy - sy, d2 = gw - pw, d3 = gh - ph;
            local += 5.0f * (d0*d0 + d1*d1 + d2*d2 + d3*d3);
            // conf (elementwise IoU)
            float ix1 = fmaxf(px1, gx1), iy1 = fmaxf(py1, gy1);
            float ix2 = fminf(px2, gx2), iy2 = fminf(py2, gy2);
            float iw = fmaxf(ix2 - ix1, 0.f), ih = fmaxf(iy2 - iy1, 0.f);
            float inter = iw * ih;
            float iou = inter / (area_p + area_g - inter + EPSF);
            float dc = iou - pconf;
            local += dc * dc;
            // cls: softmax over 20
            float cl[C_];
            float m = -1e30f;
            #pragma unroll
            for (int c = 0; c < C_; c++) { cl[c] = P[5+c]; m = fmaxf(m, cl[c]); }
            float s = 0.f;
            #pragma unroll
            for (int c = 0; c < C_; c++) { cl[c] = __expf(cl[c] - m); s += cl[c]; }
            float inv = 1.0f / s;
            float acc = 0.f;
            #pragma unroll
            for (int c = 0; c < C_; c++) { float d = T[5+c] - cl[c]*inv; acc += d*d; }
            local += acc;
        }
        local *= (1.0f / BS_);
    }

    // ---- per-block compaction: 2 atomics per block instead of 1 per thread ----
    bool isPos = valid && pos;
    bool isNeg = valid && !pos;
    unsigned long long mp = __ballot(isPos);
    unsigned long long mn = __ballot(isNeg);
    int lane = threadIdx.x & 63, wid = threadIdx.x >> 6;
    unsigned long long ltm = (1ull << lane) - 1ull;
    int ppre = __popcll(mp & ltm);
    int npre = __popcll(mn & ltm);

    __shared__ int wpo[4], wno[4];
    __shared__ int baseP, baseN;
    if (lane == 0) { wpo[wid] = __popcll(mp); wno[wid] = __popcll(mn); }
    __syncthreads();
    if (threadIdx.x == 0) {
        int tp = 0, tn = 0;
        #pragma unroll
        for (int w = 0; w < 4; w++) {
            int p = wpo[w]; wpo[w] = tp; tp += p;
            int q = wno[w]; wno[w] = tn; tn += q;
        }
        baseP = (int)atomicAdd(&cntp[b], (unsigned)tp);
        baseN = (int)atomicAdd(&cntn[b], (unsigned)tn);
    }
    __syncthreads();

    if (isPos) {
        int k = baseP + wpo[wid] + ppre;
        gtc_box[b*N_ + k] = make_float4(gx1, gy1, gx2, gy2);
        gtc_ab[b*N_ + k]  = area_g;
    } else if (isNeg) {
        int k = baseN + wno[wid] + npre;
        pnc_box[b*N_ + k] = make_float4(px1, py1, px2, py2);
        pnc_val[b*N_ + k] = (0.5f / BS_) * pconf * pconf;  // L_NOOBJ/bs * pconf^2
    }

    block_reduce_add(local, out);
}

__global__ __launch_bounds__(256) void k2_pairmax(
    const unsigned* __restrict__ cntp, const unsigned* __restrict__ cntn,
    const float4* __restrict__ gtc_box, const float* __restrict__ gtc_ab,
    const float4* __restrict__ pnc_box, unsigned* __restrict__ flags)
{
    int b = blockIdx.z, ic = blockIdx.y, jc = blockIdx.x;
    int npos = (int)cntp[b];
    int jstart = jc * JCAP;
    int jlen = min(npos - jstart, JCAP);
    if (jlen <= 0) return;   // uniform exit

    __shared__ float4 sbox[JCAP];
    __shared__ float  sab[JCAP];
    for (int j = threadIdx.x; j < jlen; j += 256) {
        sbox[j] = gtc_box[b*N_ + jstart + j];
        sab[j]  = gtc_ab[b*N_ + jstart + j];
    }
    __syncthreads();

    int nn = (int)cntn[b];
    int i = ic * ICHUNK + threadIdx.x;
    if (i >= nn) return;

    float4 p = pnc_box[b*N_ + i];
    float area_a = (p.z - p.x) * (p.w - p.y);
    float c0 = area_a + EPSF;
    float md = -1.0f;
    for (int j = 0; j < jlen; j++) {
        float4 g = sbox[j];
        float ix1 = fmaxf(p.x, g.x);
        float iy1 = fmaxf(p.y, g.y);
        float ix2 = fminf(p.z, g.z);
        float iy2 = fminf(p.w, g.w);
        float dx = fmaxf(ix2 - ix1, 0.f);
        float dy = fmaxf(iy2 - iy1, 0.f);
        float inter = dx * dy;
        float u = (c0 + sab[j]) - inter;           // area_a + area_b - inter + eps
        md = fmaxf(md, fmaf(-0.6f, u, inter));     // inter - 0.6*union >= 0  <=>  iou >= 0.6
    }
    if (md >= 0.f) flags[b*N_ + i] = 1u;           // benign same-value race across j-chunks
}

__global__ __launch_bounds__(256) void k3_noobj(
    const unsigned* __restrict__ cntn, const float* __restrict__ pnc_val,
    const unsigned* __restrict__ flags, float* __restrict__ out)
{
    int e = blockIdx.x * 256 + threadIdx.x;
    float local = 0.f;
    if (e < NE_) {
        int b = e / N_;
        int i = e - b * N_;
        if (i < (int)cntn[b] && flags[e] == 0u) local = pnc_val[e];
    }
    block_reduce_add(local, out);
}

extern "C" void kernel_launch(void* const* d_in, const int* in_sizes, int n_in,
                              void* d_out, int out_size, void* d_ws, size_t ws_size,
                              hipStream_t stream) {
    const float* pred  = (const float*)d_in[0];
    const float* gt    = (const float*)d_in[1];
    const float* anch  = (const float*)d_in[2];
    const int*   epoch = (const int*)d_in[3];
    float* out = (float*)d_out;

    char* ws = (char*)d_ws;
    unsigned* cntp   = (unsigned*)(ws + 0);
    unsigned* cntn   = (unsigned*)(ws + 64);
    float4*   gtcb   = (float4*)(ws + 128);
    float*    gtcab  = (float*)(ws + 128 + (size_t)NE_*16);
    float4*   pncb   = (float4*)(ws + 128 + (size_t)NE_*16 + (size_t)NE_*4);
    float*    pncv   = (float*)(ws + 128 + (size_t)NE_*16*2 + (size_t)NE_*4);
    unsigned* flags  = (unsigned*)(ws + 128 + (size_t)NE_*16*2 + (size_t)NE_*4*2);

    hipMemsetAsync(d_out, 0, sizeof(float), stream);
    hipMemsetAsync(ws, 0, 128, stream);

    dim3 g1(NBLK1, BS_);
    k1_elemwise<<<g1, 256, 0, stream>>>(pred, gt, anch, epoch, out,
                                        cntp, cntn, gtcb, gtcab, pncb, pncv, flags);
    dim3 g2(JCHUNKS, ICHUNKS, BS_);
    k2_pairmax<<<g2, 256, 0, stream>>>(cntp, cntn, gtcb, gtcab, pncb, flags);
    int nblk = (NE_ + 255) / 256;
    k3_noobj<<<nblk, 256, 0, stream>>>(cntn, pncv, flags, out);
}

// Round 3
// 34.775 us; speedup vs baseline: 10.6473x; 1.9415x over previous
//
#include <hip/hip_runtime.h>

#define G_ 19
#define A_ 5
#define C_ 20
#define BS_ 16
#define N_ (G_*G_*A_)        // 1805
#define NE_ (BS_*N_)         // 28880
#define NBLK1 ((N_ + 255) / 256)            // 8 blocks per batch
#define EPSF 1e-8f

// k2 tiling
#define IPT 2
#define ITILE (256*IPT)                      // 512 i per block
#define JCAP 128
#define ICH2 ((N_ + ITILE - 1)/ITILE)        // 4
#define JCH2 ((N_ + JCAP - 1)/JCAP)          // 15

__device__ __forceinline__ float sigmoidf_(float x) {
    return 1.0f / (1.0f + __expf(-x));
}

__device__ __forceinline__ void block_reduce_add(float local, float* out) {
    for (int off = 32; off; off >>= 1) local += __shfl_down(local, off);
    __shared__ float red[4];
    int wid = threadIdx.x >> 6, lane = threadIdx.x & 63;
    if (lane == 0) red[wid] = local;
    __syncthreads();
    if (threadIdx.x == 0) atomicAdd(out, red[0] + red[1] + red[2] + red[3]);
}

__global__ __launch_bounds__(256) void k1_elemwise(
    const float* __restrict__ pred, const float* __restrict__ gt,
    const float* __restrict__ anch, const int* __restrict__ epoch_p,
    float* __restrict__ out,
    unsigned* __restrict__ cntp, unsigned* __restrict__ cntn,
    float4* __restrict__ gtc_box, float* __restrict__ gtc_ab,
    float4* __restrict__ pnc_box, float* __restrict__ pnc_val,
    unsigned* __restrict__ flags)
{
    __shared__ float sp[256*25];   // 25.6 KB
    __shared__ float sg[256*25];   // 25.6 KB
    int b  = blockIdx.y;
    int n0 = blockIdx.x * 256;
    int rows = min(256, N_ - n0);
    int ndw  = rows * 25;
    const float* srcP = pred + ((size_t)b*N_ + n0)*25;
    const float* srcG = gt   + ((size_t)b*N_ + n0)*25;
    for (int d = threadIdx.x; d < ndw; d += 256) { sp[d] = srcP[d]; sg[d] = srcG[d]; }
    __syncthreads();

    int n = n0 + threadIdx.x;
    bool valid = threadIdx.x < rows;
    const float* P = sp + threadIdx.x*25;
    const float* T = sg + threadIdx.x*25;
    int e = b * N_ + n;
    float local = 0.f;

    bool pos = false;
    float gx1=0, gy1=0, gx2=0, gy2=0, area_g=0;
    float px1=0, py1=0, px2=0, py2=0, pconf=0;

    if (valid) {
        flags[e] = 0u;
        int a  = n % A_;
        int g2 = (n / A_) % G_;
        int g1 = n / (A_ * G_);
        float px = P[0], py = P[1], pw = P[2], ph = P[3], po = P[4];
        float gx = T[0], gy = T[1], gw = T[2], gh = T[3], go = T[4];
        float aw = anch[a*2+0], ah = anch[a*2+1];

        float sx  = sigmoidf_(px), sy = sigmoidf_(py);
        float pbw = __expf(pw) * aw, pbh = __expf(ph) * ah;
        float gbw = __expf(gw) * aw, gbh = __expf(gh) * ah;

        float cxp = sx + (float)g2, cyp = sy + (float)g1;
        float hwp = pbw * (0.5f * G_), hhp = pbh * (0.5f * G_);
        px1 = cxp - hwp; py1 = cyp - hhp; px2 = cxp + hwp; py2 = cyp + hhp;

        float cxg = gx + (float)g2, cyg = gy + (float)g1;
        float hwg = gbw * (0.5f * G_), hhg = gbh * (0.5f * G_);
        gx1 = cxg - hwg; gy1 = cyg - hhg; gx2 = cxg + hwg; gy2 = cyg + hhg;

        pconf = sigmoidf_(po);
        float area_p = fmaxf(px2 - px1, 0.f) * fmaxf(py2 - py1, 0.f);
        area_g = fmaxf(gx2 - gx1, 0.f) * fmaxf(gy2 - gy1, 0.f);

        if (*epoch_p < 12) {
            local += 0.01f * (px*px + py*py + pw*pw + ph*ph);
        }
        pos = go > 0.5f;
        if (pos) {
            float d0 = gx - sx, d1 = gy - sy, d2 = gw - pw, d3 = gh - ph;
            local += 5.0f * (d0*d0 + d1*d1 + d2*d2 + d3*d3);
            float ix1 = fmaxf(px1, gx1), iy1 = fmaxf(py1, gy1);
            float ix2 = fminf(px2, gx2), iy2 = fminf(py2, gy2);
            float iw = fmaxf(ix2 - ix1, 0.f), ih = fmaxf(iy2 - iy1, 0.f);
            float inter = iw * ih;
            float iou = inter / (area_p + area_g - inter + EPSF);
            float dc = iou - pconf;
            local += dc * dc;
            float cl[C_];
            float m = -1e30f;
            #pragma unroll
            for (int c = 0; c < C_; c++) { cl[c] = P[5+c]; m = fmaxf(m, cl[c]); }
            float s = 0.f;
            #pragma unroll
            for (int c = 0; c < C_; c++) { cl[c] = __expf(cl[c] - m); s += cl[c]; }
            float inv = 1.0f / s;
            float acc = 0.f;
            #pragma unroll
            for (int c = 0; c < C_; c++) { float d = T[5+c] - cl[c]*inv; acc += d*d; }
            local += acc;
        }
        local *= (1.0f / BS_);
    }

    // per-block compaction: 2 atomics per block
    bool isPos = valid && pos;
    bool isNeg = valid && !pos;
    unsigned long long mp = __ballot(isPos);
    unsigned long long mn = __ballot(isNeg);
    int lane = threadIdx.x & 63, wid = threadIdx.x >> 6;
    unsigned long long ltm = (1ull << lane) - 1ull;
    int ppre = __popcll(mp & ltm);
    int npre = __popcll(mn & ltm);

    __shared__ int wpo[4], wno[4];
    __shared__ int baseP, baseN;
    if (lane == 0) { wpo[wid] = __popcll(mp); wno[wid] = __popcll(mn); }
    __syncthreads();
    if (threadIdx.x == 0) {
        int tp = 0, tn = 0;
        #pragma unroll
        for (int w = 0; w < 4; w++) {
            int p = wpo[w]; wpo[w] = tp; tp += p;
            int q = wno[w]; wno[w] = tn; tn += q;
        }
        baseP = (int)atomicAdd(&cntp[b], (unsigned)tp);
        baseN = (int)atomicAdd(&cntn[b], (unsigned)tn);
    }
    __syncthreads();

    if (isPos) {
        int k = baseP + wpo[wid] + ppre;
        gtc_box[b*N_ + k] = make_float4(gx1, gy1, gx2, gy2);
        gtc_ab[b*N_ + k]  = area_g;
    } else if (isNeg) {
        int k = baseN + wno[wid] + npre;
        pnc_box[b*N_ + k] = make_float4(px1, py1, px2, py2);
        pnc_val[b*N_ + k] = (0.5f / BS_) * pconf * pconf;
    }

    block_reduce_add(local, out);
}

__global__ __launch_bounds__(256) void k2_pairmax(
    const unsigned* __restrict__ cntp, const unsigned* __restrict__ cntn,
    const float4* __restrict__ gtc_box, const float* __restrict__ gtc_ab,
    const float4* __restrict__ pnc_box, unsigned* __restrict__ flags)
{
    int b = blockIdx.z, ic = blockIdx.y, jc = blockIdx.x;
    int npos = (int)cntp[b];
    int jstart = jc * JCAP;
    int jlen = min(npos - jstart, JCAP);
    if (jlen <= 0) return;                        // uniform exit
    int nn = (int)cntn[b];
    if (ic * ITILE >= nn) return;                 // uniform exit

    __shared__ float4 sbox[JCAP];
    __shared__ float  sb06[JCAP];                 // -0.6 * area_b
    if (threadIdx.x < jlen) {
        sbox[threadIdx.x] = gtc_box[b*N_ + jstart + threadIdx.x];
        sb06[threadIdx.x] = -0.6f * gtc_ab[b*N_ + jstart + threadIdx.x];
    }
    __syncthreads();

    int i0 = ic * ITILE + threadIdx.x;
    int i1 = i0 + 256;
    bool v0 = i0 < nn, v1 = i1 < nn;
    float4 p0 = v0 ? pnc_box[b*N_ + i0] : make_float4(0,0,0,0);
    float4 p1 = v1 ? pnc_box[b*N_ + i1] : make_float4(0,0,0,0);
    float c0 = (p0.z - p0.x) * (p0.w - p0.y) + EPSF;
    float c1 = (p1.z - p1.x) * (p1.w - p1.y) + EPSF;

    float md0 = -1e30f, md1 = -1e30f;
    for (int j = 0; j < jlen; j++) {
        float4 g = sbox[j];
        float t = sb06[j];
        float ax0 = fmaxf(p0.x, g.x), ay0 = fmaxf(p0.y, g.y);
        float bx0 = fminf(p0.z, g.z), by0 = fminf(p0.w, g.w);
        float in0 = fmaxf(bx0 - ax0, 0.f) * fmaxf(by0 - ay0, 0.f);
        md0 = fmaxf(md0, fmaf(1.6f, in0, t));     // 1.6*inter - 0.6*area_b
        float ax1 = fmaxf(p1.x, g.x), ay1 = fmaxf(p1.y, g.y);
        float bx1 = fminf(p1.z, g.z), by1 = fminf(p1.w, g.w);
        float in1 = fmaxf(bx1 - ax1, 0.f) * fmaxf(by1 - ay1, 0.f);
        md1 = fmaxf(md1, fmaf(1.6f, in1, t));
    }
    // iou >= 0.6  <=>  1.6*inter - 0.6*area_b >= 0.6*(area_a + eps)
    if (v0 && md0 >= 0.6f * c0) flags[b*N_ + i0] = 1u;   // benign same-value race
    if (v1 && md1 >= 0.6f * c1) flags[b*N_ + i1] = 1u;
}

__global__ __launch_bounds__(256) void k3_noobj(
    const unsigned* __restrict__ cntn, const float* __restrict__ pnc_val,
    const unsigned* __restrict__ flags, float* __restrict__ out)
{
    int b = blockIdx.y;
    int i = blockIdx.x * 256 + threadIdx.x;
    float local = 0.f;
    if (i < (int)cntn[b] && flags[b*N_ + i] == 0u) local = pnc_val[b*N_ + i];
    block_reduce_add(local, out);
}

extern "C" void kernel_launch(void* const* d_in, const int* in_sizes, int n_in,
                              void* d_out, int out_size, void* d_ws, size_t ws_size,
                              hipStream_t stream) {
    const float* pred  = (const float*)d_in[0];
    const float* gt    = (const float*)d_in[1];
    const float* anch  = (const float*)d_in[2];
    const int*   epoch = (const int*)d_in[3];
    float* out = (float*)d_out;

    char* ws = (char*)d_ws;
    unsigned* cntp   = (unsigned*)(ws + 0);
    unsigned* cntn   = (unsigned*)(ws + 64);
    float4*   gtcb   = (float4*)(ws + 128);
    float*    gtcab  = (float*)(ws + 128 + (size_t)NE_*16);
    float4*   pncb   = (float4*)(ws + 128 + (size_t)NE_*16 + (size_t)NE_*4);
    float*    pncv   = (float*)(ws + 128 + (size_t)NE_*16*2 + (size_t)NE_*4);
    unsigned* flags  = (unsigned*)(ws + 128 + (size_t)NE_*16*2 + (size_t)NE_*4*2);

    hipMemsetAsync(d_out, 0, sizeof(float), stream);
    hipMemsetAsync(ws, 0, 128, stream);

    dim3 g1(NBLK1, BS_);
    k1_elemwise<<<g1, 256, 0, stream>>>(pred, gt, anch, epoch, out,
                                        cntp, cntn, gtcb, gtcab, pncb, pncv, flags);
    dim3 g2(JCH2, ICH2, BS_);
    k2_pairmax<<<g2, 256, 0, stream>>>(cntp, cntn, gtcb, gtcab, pncb, flags);
    dim3 g3(NBLK1, BS_);
    k3_noobj<<<g3, 256, 0, stream>>>(cntn, pncv, flags, out);
}